// Round 2
// baseline (1722.002 us; speedup 1.0000x reference)
//
#include <hip/hip_runtime.h>
#include <math.h>

typedef __bf16 bf16;
typedef __bf16 bf16x8 __attribute__((ext_vector_type(8)));
typedef float  f32x4  __attribute__((ext_vector_type(4)));

#define NTOK  4096
#define SEQ   2048
#define DM    1024
#define NHEAD 16
#define NKVH  4
#define HDIM  64
#define NEXP  8
#define FFD   4096
#define PMAX  9216   // 8192 pairs + 8*128 alignment slack

__device__ __forceinline__ bf16x8 zero8() {
    bf16x8 z;
#pragma unroll
    for (int i = 0; i < 8; i++) z[i] = (bf16)0.0f;
    return z;
}

// ---------------- transpose + cast: W (R x C) f32 -> Wt (C x R) bf16 ----------
__global__ __launch_bounds__(256)
void transpose_cast(const float* __restrict__ W, bf16* __restrict__ Wt,
                    int R, int C, int ldo, size_t in_bs, size_t out_bs)
{
    __shared__ float tile[32][33];
    const float* Wb = W + (size_t)blockIdx.z * in_bs;
    bf16* Ob = Wt + (size_t)blockIdx.z * out_bs;
    int c0 = blockIdx.x * 32, r0 = blockIdx.y * 32;
    int tx = threadIdx.x & 31, ty = threadIdx.x >> 5;   // 32 x 8
#pragma unroll
    for (int i = 0; i < 4; i++)
        tile[ty + i*8][tx] = Wb[(size_t)(r0 + ty + i*8) * C + c0 + tx];
    __syncthreads();
#pragma unroll
    for (int i = 0; i < 4; i++)
        Ob[(size_t)(c0 + ty + i*8) * ldo + r0 + tx] = (bf16)tile[tx][ty + i*8];
}

// ---------------- layernorm (f32 in -> bf16 out), one block per token --------
__device__ __forceinline__ void block_reduce2(float& s, float& ss) {
#pragma unroll
    for (int w = 32; w; w >>= 1) { s += __shfl_xor(s, w, 64); ss += __shfl_xor(ss, w, 64); }
    __shared__ float red[8];
    int t = threadIdx.x;
    if ((t & 63) == 0) { red[t >> 6] = s; red[4 + (t >> 6)] = ss; }
    __syncthreads();
    s  = red[0] + red[1] + red[2] + red[3];
    ss = red[4] + red[5] + red[6] + red[7];
}

__global__ __launch_bounds__(256)
void ln_bf16_kernel(const float* __restrict__ x, const float* __restrict__ g,
                    const float* __restrict__ b, bf16* __restrict__ out)
{
    int tok = blockIdx.x, t = threadIdx.x;
    const float* xr = x + (size_t)tok * DM;
    float v[4], s = 0.f, ss = 0.f;
#pragma unroll
    for (int i = 0; i < 4; i++) { v[i] = xr[t + 256*i]; s += v[i]; ss += v[i]*v[i]; }
    block_reduce2(s, ss);
    float mean = s * (1.0f/DM);
    float var  = ss * (1.0f/DM) - mean*mean;
    float rs = rsqrtf(var + 1e-5f);
#pragma unroll
    for (int i = 0; i < 4; i++) {
        int d = t + 256*i;
        out[(size_t)tok*DM + d] = (bf16)((v[i]-mean)*rs*g[d] + b[d]);
    }
}

// ---------------- generic bf16 MFMA GEMM: C = A(MxK) * Bt(NxK)^T -------------
// 128x128 tile, BK=32, 4 waves (2x2), each wave 64x64 via 4x4 16x16x32 MFMAs.
__global__ __launch_bounds__(256, 2)
void gemm_bf16(const bf16* __restrict__ A, int lda,
               const bf16* __restrict__ Bt, int ldb, int NB,
               int M, int N, int K,
               const float* __restrict__ bias,
               const float* __restrict__ addsrc,
               float* __restrict__ Cf, bf16* __restrict__ Cb, int ldc)
{
    __shared__ __align__(16) bf16 As[128*32];
    __shared__ __align__(16) bf16 Bs[128*32];
    const int t = threadIdx.x;
    const int m0 = blockIdx.y * 128, n0 = blockIdx.x * 128;
    const int lane = t & 63, wave = t >> 6;
    const int wm = (wave >> 1) * 64, wn = (wave & 1) * 64;
    const int lr = lane & 15, lq = lane >> 4;
    f32x4 acc[4][4];
#pragma unroll
    for (int i = 0; i < 4; i++)
#pragma unroll
        for (int j = 0; j < 4; j++)
#pragma unroll
            for (int r = 0; r < 4; r++) acc[i][j][r] = 0.f;
    const int srow = t >> 2, scol = (t & 3) * 8;

    for (int k0 = 0; k0 < K; k0 += 32) {
        bf16x8 a0 = zero8(), a1 = zero8(), b0 = zero8(), b1 = zero8();
        int ar0 = m0 + srow, ar1 = ar0 + 64;
        int br0 = n0 + srow, br1 = br0 + 64;
        if (ar0 < M)  a0 = *(const bf16x8*)&A [(size_t)ar0*lda + k0 + scol];
        if (ar1 < M)  a1 = *(const bf16x8*)&A [(size_t)ar1*lda + k0 + scol];
        if (br0 < NB) b0 = *(const bf16x8*)&Bt[(size_t)br0*ldb + k0 + scol];
        if (br1 < NB) b1 = *(const bf16x8*)&Bt[(size_t)br1*ldb + k0 + scol];
        __syncthreads();
        *(bf16x8*)&As[srow*32 + scol]      = a0;
        *(bf16x8*)&As[(srow+64)*32 + scol] = a1;
        *(bf16x8*)&Bs[srow*32 + scol]      = b0;
        *(bf16x8*)&Bs[(srow+64)*32 + scol] = b1;
        __syncthreads();
        bf16x8 af[4], bg[4];
#pragma unroll
        for (int i = 0; i < 4; i++) af[i] = *(const bf16x8*)&As[(wm + i*16 + lr)*32 + lq*8];
#pragma unroll
        for (int j = 0; j < 4; j++) bg[j] = *(const bf16x8*)&Bs[(wn + j*16 + lr)*32 + lq*8];
#pragma unroll
        for (int i = 0; i < 4; i++)
#pragma unroll
            for (int j = 0; j < 4; j++)
                acc[i][j] = __builtin_amdgcn_mfma_f32_16x16x32_bf16(af[i], bg[j], acc[i][j], 0, 0, 0);
    }
#pragma unroll
    for (int i = 0; i < 4; i++) {
#pragma unroll
        for (int j = 0; j < 4; j++) {
            int col = n0 + wn + j*16 + lr;
            if (col >= N) continue;
            float bv = bias ? bias[col] : 0.f;
#pragma unroll
            for (int r = 0; r < 4; r++) {
                int m = m0 + wm + i*16 + lq*4 + r;
                if (m >= M) continue;
                float v = acc[i][j][r] + bv;
                if (addsrc) v += addsrc[(size_t)m*ldc + col];
                if (Cf) Cf[(size_t)m*ldc + col] = v;
                if (Cb) Cb[(size_t)m*ldc + col] = (bf16)v;
            }
        }
    }
}

// ---------------- grouped MoE GEMM (expert chosen by 128-aligned row block) --
__global__ __launch_bounds__(256, 2)
void moe_gemm(const bf16* __restrict__ A, int lda,
              const bf16* __restrict__ WtBase, size_t wstride, int ldb,
              const float* __restrict__ biasBase, int biasStride,
              const int* __restrict__ off, int N, int K,
              bf16* __restrict__ Cb, float* __restrict__ Cf, int ldc, int gelu)
{
    const int m0 = blockIdx.y * 128;
    const int total = off[8];
    if (m0 >= total) return;
    int e = 0;
    while (e < 7 && m0 >= off[e+1]) e++;
    const bf16*  Bt   = WtBase  + (size_t)e * wstride;
    const float* bias = biasBase + (size_t)e * biasStride;

    __shared__ __align__(16) bf16 As[128*32];
    __shared__ __align__(16) bf16 Bs[128*32];
    const int t = threadIdx.x;
    const int n0 = blockIdx.x * 128;
    const int lane = t & 63, wave = t >> 6;
    const int wm = (wave >> 1) * 64, wn = (wave & 1) * 64;
    const int lr = lane & 15, lq = lane >> 4;
    f32x4 acc[4][4];
#pragma unroll
    for (int i = 0; i < 4; i++)
#pragma unroll
        for (int j = 0; j < 4; j++)
#pragma unroll
            for (int r = 0; r < 4; r++) acc[i][j][r] = 0.f;
    const int srow = t >> 2, scol = (t & 3) * 8;

    for (int k0 = 0; k0 < K; k0 += 32) {
        bf16x8 a0 = *(const bf16x8*)&A [(size_t)(m0+srow)    *lda + k0 + scol];
        bf16x8 a1 = *(const bf16x8*)&A [(size_t)(m0+srow+64) *lda + k0 + scol];
        bf16x8 b0 = *(const bf16x8*)&Bt[(size_t)(n0+srow)    *ldb + k0 + scol];
        bf16x8 b1 = *(const bf16x8*)&Bt[(size_t)(n0+srow+64) *ldb + k0 + scol];
        __syncthreads();
        *(bf16x8*)&As[srow*32 + scol]      = a0;
        *(bf16x8*)&As[(srow+64)*32 + scol] = a1;
        *(bf16x8*)&Bs[srow*32 + scol]      = b0;
        *(bf16x8*)&Bs[(srow+64)*32 + scol] = b1;
        __syncthreads();
        bf16x8 af[4], bg[4];
#pragma unroll
        for (int i = 0; i < 4; i++) af[i] = *(const bf16x8*)&As[(wm + i*16 + lr)*32 + lq*8];
#pragma unroll
        for (int j = 0; j < 4; j++) bg[j] = *(const bf16x8*)&Bs[(wn + j*16 + lr)*32 + lq*8];
#pragma unroll
        for (int i = 0; i < 4; i++)
#pragma unroll
            for (int j = 0; j < 4; j++)
                acc[i][j] = __builtin_amdgcn_mfma_f32_16x16x32_bf16(af[i], bg[j], acc[i][j], 0, 0, 0);
    }
#pragma unroll
    for (int i = 0; i < 4; i++) {
#pragma unroll
        for (int j = 0; j < 4; j++) {
            int col = n0 + wn + j*16 + lr;
            float bv = bias[col];
#pragma unroll
            for (int r = 0; r < 4; r++) {
                int m = m0 + wm + i*16 + lq*4 + r;
                float v = acc[i][j][r] + bv;
                if (gelu) v = 0.5f * v * (1.0f + erff(v * 0.70710678118f));
                if (Cb) Cb[(size_t)m*ldc + col] = (bf16)v;
                if (Cf) Cf[(size_t)m*ldc + col] = v;
            }
        }
    }
}

// ---------------- RoPE --------------------------------------------------------
__global__ __launch_bounds__(256)
void rope_q_kernel(float* __restrict__ q)
{
    int tok = blockIdx.x, t = threadIdx.x;
    int pos = tok & (SEQ - 1);
    const float LOG1e4_32 = 0.2878231366f;  // ln(10000)/32
#pragma unroll
    for (int i = 0; i < 2; i++) {
        int p = t + 256*i;          // 0..511 = 16 heads * 32 freqs
        int hh = p >> 5, fi = p & 31;
        float inv = __expf(-(float)fi * LOG1e4_32);
        float ang = (float)pos * inv;
        float c = cosf(ang), sn = sinf(ang);
        float* base = q + (size_t)tok*DM + hh*HDIM + 2*fi;
        float x1 = base[0], x2 = base[1];
        base[0] = x1*c - x2*sn;
        base[1] = x1*sn + x2*c;
    }
}

__global__ __launch_bounds__(256)
void rope_kv_kernel(const float* __restrict__ kv, float* __restrict__ kr, float* __restrict__ vr)
{
    int tok = blockIdx.x, t = threadIdx.x;
    int pos = tok & (SEQ - 1);
    int kvh = t >> 6, d = t & 63;
    // v: kv[..., kvh, hd, 1]
    vr[(size_t)tok*(NKVH*HDIM) + kvh*HDIM + d] = kv[(size_t)tok*512 + (size_t)(kvh*HDIM + d)*2 + 1];
    if (t < 128) {
        int h2 = t >> 5, fi = t & 31;
        const float LOG1e4_32 = 0.2878231366f;
        float inv = __expf(-(float)fi * LOG1e4_32);
        float ang = (float)pos * inv;
        float c = cosf(ang), sn = sinf(ang);
        const float* kb = kv + (size_t)tok*512 + (size_t)(h2*HDIM + 2*fi)*2;
        float x1 = kb[0], x2 = kb[2];
        float* ob = kr + (size_t)tok*(NKVH*HDIM) + h2*HDIM + 2*fi;
        ob[0] = x1*c - x2*sn;
        ob[1] = x1*sn + x2*c;
    }
}

// ---------------- causal flash attention (vector f32), GQA 16q/4kv -----------
__global__ __launch_bounds__(256)
void attn_kernel(const float* __restrict__ q, const float* __restrict__ kr,
                 const float* __restrict__ vr, bf16* __restrict__ o)
{
    __shared__ __align__(16) float Qt[32][68];
    __shared__ __align__(16) float Kt[32][68];
    __shared__ __align__(16) float Vt[32][68];
    __shared__ float Pt[32][36];
    int qt = blockIdx.x;                 // 0..63 query tiles of 32
    int bh = blockIdx.y;                 // 0..31
    int b = bh >> 4, h = bh & 15, kvh = h >> 2;
    int t = threadIdx.x;
    int r = t >> 3, sub = t & 7;         // 8 threads per query row
    int tok0 = b * SEQ;
#pragma unroll
    for (int i = 0; i < 8; i++) {
        int f = t + 256*i, rr = f >> 6, d = f & 63;
        Qt[rr][d] = q[(size_t)(tok0 + qt*32 + rr)*DM + h*HDIM + d] * 0.125f;
    }
    float O[8];
#pragma unroll
    for (int i = 0; i < 8; i++) O[i] = 0.f;
    float mrow = -1e30f, lrow = 0.f;
    int qg = qt*32 + r;

    for (int kt = 0; kt <= qt; kt++) {
        __syncthreads();
#pragma unroll
        for (int i = 0; i < 8; i++) {
            int f = t + 256*i, rr = f >> 6, d = f & 63;
            size_t src = (size_t)(tok0 + kt*32 + rr)*(NKVH*HDIM) + kvh*HDIM + d;
            Kt[rr][d] = kr[src];
            Vt[rr][d] = vr[src];
        }
        __syncthreads();
        int c = sub*4;
        float s0=0.f, s1=0.f, s2=0.f, s3=0.f;
#pragma unroll
        for (int d = 0; d < 64; d += 4) {
            float4 qv = *(const float4*)&Qt[r][d];
            float4 k0 = *(const float4*)&Kt[c  ][d];
            float4 k1 = *(const float4*)&Kt[c+1][d];
            float4 k2 = *(const float4*)&Kt[c+2][d];
            float4 k3 = *(const float4*)&Kt[c+3][d];
            s0 += qv.x*k0.x + qv.y*k0.y + qv.z*k0.z + qv.w*k0.w;
            s1 += qv.x*k1.x + qv.y*k1.y + qv.z*k1.z + qv.w*k1.w;
            s2 += qv.x*k2.x + qv.y*k2.y + qv.z*k2.z + qv.w*k2.w;
            s3 += qv.x*k3.x + qv.y*k3.y + qv.z*k3.z + qv.w*k3.w;
        }
        if (kt == qt) {
            int kb = kt*32 + c;
            if (kb + 0 > qg) s0 = -1e30f;
            if (kb + 1 > qg) s1 = -1e30f;
            if (kb + 2 > qg) s2 = -1e30f;
            if (kb + 3 > qg) s3 = -1e30f;
        }
        float mx = fmaxf(fmaxf(s0, s1), fmaxf(s2, s3));
#pragma unroll
        for (int w = 1; w <= 4; w <<= 1) mx = fmaxf(mx, __shfl_xor(mx, w, 64));
        float mnew = fmaxf(mrow, mx);
        float alpha = __expf(mrow - mnew);
        float p0 = __expf(s0 - mnew), p1 = __expf(s1 - mnew);
        float p2 = __expf(s2 - mnew), p3 = __expf(s3 - mnew);
        Pt[r][c+0] = p0; Pt[r][c+1] = p1; Pt[r][c+2] = p2; Pt[r][c+3] = p3;
        float ps = p0 + p1 + p2 + p3;
#pragma unroll
        for (int w = 1; w <= 4; w <<= 1) ps += __shfl_xor(ps, w, 64);
        lrow = lrow * alpha + ps;
        mrow = mnew;
#pragma unroll
        for (int i = 0; i < 8; i++) O[i] *= alpha;
        __syncthreads();
#pragma unroll 4
        for (int kk = 0; kk < 32; kk++) {
            float p = Pt[r][kk];
            float4 v0 = *(const float4*)&Vt[kk][sub*8];
            float4 v1 = *(const float4*)&Vt[kk][sub*8 + 4];
            O[0] += p*v0.x; O[1] += p*v0.y; O[2] += p*v0.z; O[3] += p*v0.w;
            O[4] += p*v1.x; O[5] += p*v1.y; O[6] += p*v1.z; O[7] += p*v1.w;
        }
    }
    float inv = 1.0f / lrow;
    bf16* ob = o + (size_t)(tok0 + qt*32 + r)*DM + h*HDIM + sub*8;
#pragma unroll
    for (int i = 0; i < 8; i++) ob[i] = (bf16)(O[i] * inv);
}

// ---------------- fused f32 LN + router + top-2 (one wave per token) ---------
// Reads x2 (f32), applies ln2 in f32, computes logits in f32. Avoids bf16
// quantization noise on logits -> expert top-2 selection matches reference.
__global__ __launch_bounds__(256)
void router_kernel(const float* __restrict__ x2, const float* __restrict__ lg,
                   const float* __restrict__ lb, const float* __restrict__ rw,
                   float* __restrict__ logits, int* __restrict__ topi,
                   float* __restrict__ topg, int* __restrict__ cnt)
{
    int tok = blockIdx.x * 4 + (threadIdx.x >> 6);
    int lane = threadIdx.x & 63;
    const float* xr = x2 + (size_t)tok * DM;
    float v[16], s = 0.f, ss = 0.f;
#pragma unroll
    for (int i = 0; i < 16; i++) {
        v[i] = xr[lane + 64*i];
        s += v[i]; ss += v[i]*v[i];
    }
#pragma unroll
    for (int w = 32; w; w >>= 1) { s += __shfl_xor(s, w, 64); ss += __shfl_xor(ss, w, 64); }
    float mean = s * (1.0f/DM);
    float var  = ss * (1.0f/DM) - mean*mean;
    float rs = rsqrtf(var + 1e-5f);
    float acc[8];
#pragma unroll
    for (int e = 0; e < 8; e++) acc[e] = 0.f;
#pragma unroll
    for (int i = 0; i < 16; i++) {
        int d = lane + 64*i;
        float hn = (v[i] - mean) * rs * lg[d] + lb[d];
        const float* w = rw + (size_t)d * 8;
#pragma unroll
        for (int e = 0; e < 8; e++) acc[e] += hn * w[e];
    }
#pragma unroll
    for (int e = 0; e < 8; e++) {
        float t = acc[e];
#pragma unroll
        for (int w = 32; w; w >>= 1) t += __shfl_xor(t, w, 64);
        acc[e] = t;
    }
    if (lane == 0) {
#pragma unroll
        for (int e = 0; e < 8; e++) logits[(size_t)tok*8 + e] = acc[e];
        int i1 = 0;
        for (int e = 1; e < 8; e++) if (acc[e] > acc[i1]) i1 = e;
        int i2 = (i1 == 0) ? 1 : 0;
        for (int e = 0; e < 8; e++) if (e != i1 && acc[e] > acc[i2]) i2 = e;
        float ex = __expf(acc[i2] - acc[i1]);
        float g1 = 1.f / (1.f + ex);
        topi[tok*2] = i1; topi[tok*2 + 1] = i2;
        topg[tok*2] = g1; topg[tok*2 + 1] = 1.f - g1;
        atomicAdd(&cnt[i1], 1);
        atomicAdd(&cnt[i2], 1);
    }
}

__global__ void scan_kernel(int* ctrl)   // ctrl: [0..7]=cnt [8..15]=fill [16..24]=off
{
    if (threadIdx.x == 0) {
        int run = 0;
#pragma unroll
        for (int e = 0; e < 8; e++) {
            ctrl[16 + e] = run;
            run += (ctrl[e] + 127) & ~127;
        }
        ctrl[24] = run;
    }
}

__global__ __launch_bounds__(256)
void fill_kernel(const int* __restrict__ topi, const float* __restrict__ topg,
                 int* ctrl, int* __restrict__ pair_token, int* __restrict__ token_slot)
{
    int tok = blockIdx.x * 256 + threadIdx.x;
    int* fill = ctrl + 8;
    const int* off = ctrl + 16;
#pragma unroll
    for (int kth = 0; kth < 2; kth++) {
        int e = topi[tok*2 + kth];
        int slot = off[e] + atomicAdd(&fill[e], 1);
        pair_token[slot] = tok;
        token_slot[tok*2 + kth] = slot;
    }
}

__global__ __launch_bounds__(256)
void gather_kernel(const bf16* __restrict__ h2, const int* __restrict__ pair_token,
                   bf16* __restrict__ Am)
{
    int slot = blockIdx.x, t = threadIdx.x;
    int tok = pair_token[slot];
    uint2* dst = (uint2*)(Am + (size_t)slot * DM);
    if (tok >= 0) {
        const uint2* src = (const uint2*)(h2 + (size_t)tok * DM);
        dst[t] = src[t];
    } else {
        uint2 z; z.x = 0u; z.y = 0u;
        dst[t] = z;
    }
}

// ---------------- final: gate-combine pairs, moe layernorm, residual ---------
__global__ __launch_bounds__(256)
void final_kernel(const float* __restrict__ x2, const float* __restrict__ y,
                  const int* __restrict__ token_slot, const float* __restrict__ topg,
                  const float* __restrict__ g, const float* __restrict__ b,
                  float* __restrict__ out)
{
    int tok = blockIdx.x, t = threadIdx.x;
    int s0 = token_slot[tok*2], s1 = token_slot[tok*2 + 1];
    float g0 = topg[tok*2], g1 = topg[tok*2 + 1];
    float v[4], s = 0.f, ss = 0.f;
#pragma unroll
    for (int i = 0; i < 4; i++) {
        int d = t + 256*i;
        float mv = g0 * y[(size_t)s0*DM + d] + g1 * y[(size_t)s1*DM + d];
        v[i] = mv; s += mv; ss += mv*mv;
    }
    block_reduce2(s, ss);
    float mean = s * (1.0f/DM);
    float var  = ss * (1.0f/DM) - mean*mean;
    float rs = rsqrtf(var + 1e-5f);
#pragma unroll
    for (int i = 0; i < 4; i++) {
        int d = t + 256*i;
        out[(size_t)tok*DM + d] = x2[(size_t)tok*DM + d] + (v[i]-mean)*rs*g[d] + b[d];
    }
}

// =============================================================================
extern "C" void kernel_launch(void* const* d_in, const int* in_sizes, int n_in,
                              void* d_out, int out_size, void* d_ws, size_t ws_size,
                              hipStream_t stream)
{
    const float* x        = (const float*)d_in[0];
    const float* ln1_g    = (const float*)d_in[1];
    const float* ln1_b    = (const float*)d_in[2];
    const float* q_a_w    = (const float*)d_in[3];
    const float* q_b_w    = (const float*)d_in[4];
    const float* kv_a_w   = (const float*)d_in[5];
    const float* kv_b_w   = (const float*)d_in[6];
    const float* out_w    = (const float*)d_in[7];
    const float* out_b    = (const float*)d_in[8];
    const float* ln2_g    = (const float*)d_in[9];
    const float* ln2_b    = (const float*)d_in[10];
    const float* router_w = (const float*)d_in[11];
    const float* fc_w     = (const float*)d_in[12];
    const float* fc_b     = (const float*)d_in[13];
    const float* proj_w   = (const float*)d_in[14];
    const float* proj_b   = (const float*)d_in[15];
    const float* moe_ln_g = (const float*)d_in[16];
    const float* moe_ln_b = (const float*)d_in[17];

    char* ws = (char*)d_ws;
    size_t cur = 0;
    auto alloc = [&](size_t bytes) -> void* {
        void* p = ws + cur;
        cur += (bytes + 255) & ~(size_t)255;
        return p;
    };
    bf16*  h1    = (bf16*) alloc((size_t)NTOK*DM*2);
    bf16*  latwT = (bf16*) alloc((size_t)96*1024*2);   // rows 0-63 qa^T, 64-95 kva^T
    bf16*  qbT   = (bf16*) alloc((size_t)1024*64*2);
    bf16*  kvbT  = (bf16*) alloc((size_t)512*32*2);
    bf16*  outwT = (bf16*) alloc((size_t)1024*1024*2);
    bf16*  fcT   = (bf16*) alloc((size_t)NEXP*FFD*DM*2);
    bf16*  projT = (bf16*) alloc((size_t)NEXP*DM*FFD*2);
    bf16*  latb  = (bf16*) alloc((size_t)NTOK*96*2);
    float* qf    = (float*)alloc((size_t)NTOK*DM*4);
    float* kvf   = (float*)alloc((size_t)NTOK*512*4);
    float* krf   = (float*)alloc((size_t)NTOK*NKVH*HDIM*4);
    float* vrf   = (float*)alloc((size_t)NTOK*NKVH*HDIM*4);
    bf16*  ob    = (bf16*) alloc((size_t)NTOK*DM*2);
    float* x2f   = (float*)alloc((size_t)NTOK*DM*4);
    bf16*  h2    = (bf16*) alloc((size_t)NTOK*DM*2);
    int*   topi  = (int*)  alloc((size_t)NTOK*2*4);
    float* topg  = (float*)alloc((size_t)NTOK*2*4);
    int*   ctrl  = (int*)  alloc(256);
    int*   pair_token = (int*)alloc((size_t)PMAX*4);
    int*   token_slot = (int*)alloc((size_t)NTOK*2*4);
    bf16*  Am    = (bf16*) alloc((size_t)PMAX*DM*2);
    bf16*  hid   = (bf16*) alloc((size_t)PMAX*FFD*2);
    float* yb    = (float*)alloc((size_t)PMAX*DM*4);
    (void)ws_size; (void)in_sizes; (void)n_in; (void)out_size;

    float* out_x      = (float*)d_out;
    float* out_logits = (float*)d_out + (size_t)NTOK*DM;

    dim3 blk(256);
    // weight transpose+cast (f32 KxN -> bf16 NxK)
    transpose_cast<<<dim3(2,32,1),  blk, 0, stream>>>(q_a_w,  latwT,            1024,   64, 1024, 0, 0);
    transpose_cast<<<dim3(1,32,1),  blk, 0, stream>>>(kv_a_w, latwT + 64*1024,  1024,   32, 1024, 0, 0);
    transpose_cast<<<dim3(32,2,1),  blk, 0, stream>>>(q_b_w,  qbT,                64, 1024,   64, 0, 0);
    transpose_cast<<<dim3(16,1,1),  blk, 0, stream>>>(kv_b_w, kvbT,               32,  512,   32, 0, 0);
    transpose_cast<<<dim3(32,32,1), blk, 0, stream>>>(out_w,  outwT,            1024, 1024, 1024, 0, 0);
    transpose_cast<<<dim3(128,32,8),blk, 0, stream>>>(fc_w,   fcT,              1024, 4096, 1024,
                                                      (size_t)1024*4096, (size_t)4096*1024);
    transpose_cast<<<dim3(32,128,8),blk, 0, stream>>>(proj_w, projT,            4096, 1024, 4096,
                                                      (size_t)4096*1024, (size_t)1024*4096);
    // ln1 -> h1
    ln_bf16_kernel<<<NTOK, blk, 0, stream>>>(x, ln1_g, ln1_b, h1);
    // latents: h1 @ [qa|kva] -> latb (4096x96 bf16)
    gemm_bf16<<<dim3(1,32), blk, 0, stream>>>(h1, 1024, latwT, 1024, 96, NTOK, 96, 1024,
                                              nullptr, nullptr, nullptr, latb, 96);
    // q = lat_q @ q_b  (K=64)
    gemm_bf16<<<dim3(8,32), blk, 0, stream>>>(latb, 96, qbT, 64, 1024, NTOK, 1024, 64,
                                              nullptr, nullptr, qf, nullptr, 1024);
    // kv = lat_kv @ kv_b (K=32)
    gemm_bf16<<<dim3(4,32), blk, 0, stream>>>(latb + 64, 96, kvbT, 32, 512, NTOK, 512, 32,
                                              nullptr, nullptr, kvf, nullptr, 512);
    rope_q_kernel<<<NTOK, blk, 0, stream>>>(qf);
    rope_kv_kernel<<<NTOK, blk, 0, stream>>>(kvf, krf, vrf);
    attn_kernel<<<dim3(64,32), blk, 0, stream>>>(qf, krf, vrf, ob);
    // out proj + residual -> x2
    gemm_bf16<<<dim3(8,32), blk, 0, stream>>>(ob, 1024, outwT, 1024, 1024, NTOK, 1024, 1024,
                                              out_b, x, x2f, nullptr, 1024);
    // ln2 -> h2 (bf16 copy for expert GEMM input)
    ln_bf16_kernel<<<NTOK, blk, 0, stream>>>(x2f, ln2_g, ln2_b, h2);
    // routing (f32 LN fused inside — bf16 h2 noise must not flip top-2)
    hipMemsetAsync(ctrl, 0, 64, stream);
    router_kernel<<<NTOK/4, blk, 0, stream>>>(x2f, ln2_g, ln2_b, router_w,
                                              out_logits, topi, topg, ctrl);
    scan_kernel<<<1, 64, 0, stream>>>(ctrl);
    hipMemsetAsync(pair_token, 0xFF, (size_t)PMAX*4, stream);
    fill_kernel<<<NTOK/256, blk, 0, stream>>>(topi, topg, ctrl, pair_token, token_slot);
    gather_kernel<<<PMAX, blk, 0, stream>>>(h2, pair_token, Am);
    // MoE fc (gelu fused) and proj
    moe_gemm<<<dim3(FFD/128, PMAX/128), blk, 0, stream>>>(Am, 1024, fcT, (size_t)FFD*DM, 1024,
                                                          fc_b, FFD, ctrl + 16, FFD, 1024,
                                                          hid, nullptr, FFD, 1);
    moe_gemm<<<dim3(DM/128, PMAX/128), blk, 0, stream>>>(hid, FFD, projT, (size_t)DM*FFD, FFD,
                                                         proj_b, DM, ctrl + 16, DM, FFD,
                                                         nullptr, yb, DM, 0);
    // combine + moe layernorm + residual
    final_kernel<<<NTOK, blk, 0, stream>>>(x2f, yb, token_slot, topg, moe_ln_g, moe_ln_b, out_x);
}

// Round 3
// 1056.101 us; speedup vs baseline: 1.6305x; 1.6305x over previous
//
#include <hip/hip_runtime.h>
#include <math.h>

typedef __bf16 bf16;
typedef __bf16 bf16x8 __attribute__((ext_vector_type(8)));
typedef float  f32x4  __attribute__((ext_vector_type(4)));

#define NTOK  4096
#define SEQ   2048
#define DM    1024
#define NHEAD 16
#define NKVH  4
#define HDIM  64
#define NEXP  8
#define FFD   4096
#define PMAX  9216   // 8192 pairs + 8*128 alignment slack

__device__ __forceinline__ bf16x8 zero8() {
    bf16x8 z;
#pragma unroll
    for (int i = 0; i < 8; i++) z[i] = (bf16)0.0f;
    return z;
}

// ---------------- transpose + cast: W (R x C) f32 -> Wt (C x R) bf16 ----------
__global__ __launch_bounds__(256)
void transpose_cast(const float* __restrict__ W, bf16* __restrict__ Wt,
                    int R, int C, int ldo, size_t in_bs, size_t out_bs)
{
    __shared__ float tile[32][33];
    const float* Wb = W + (size_t)blockIdx.z * in_bs;
    bf16* Ob = Wt + (size_t)blockIdx.z * out_bs;
    int c0 = blockIdx.x * 32, r0 = blockIdx.y * 32;
    int tx = threadIdx.x & 31, ty = threadIdx.x >> 5;   // 32 x 8
#pragma unroll
    for (int i = 0; i < 4; i++)
        tile[ty + i*8][tx] = Wb[(size_t)(r0 + ty + i*8) * C + c0 + tx];
    __syncthreads();
#pragma unroll
    for (int i = 0; i < 4; i++)
        Ob[(size_t)(c0 + ty + i*8) * ldo + r0 + tx] = (bf16)tile[tx][ty + i*8];
}

// ---------------- layernorm (f32 in -> bf16 out), one block per token --------
__device__ __forceinline__ void block_reduce2(float& s, float& ss) {
#pragma unroll
    for (int w = 32; w; w >>= 1) { s += __shfl_xor(s, w, 64); ss += __shfl_xor(ss, w, 64); }
    __shared__ float red[8];
    int t = threadIdx.x;
    if ((t & 63) == 0) { red[t >> 6] = s; red[4 + (t >> 6)] = ss; }
    __syncthreads();
    s  = red[0] + red[1] + red[2] + red[3];
    ss = red[4] + red[5] + red[6] + red[7];
}

__global__ __launch_bounds__(256)
void ln_bf16_kernel(const float* __restrict__ x, const float* __restrict__ g,
                    const float* __restrict__ b, bf16* __restrict__ out)
{
    int tok = blockIdx.x, t = threadIdx.x;
    const float* xr = x + (size_t)tok * DM;
    float v[4], s = 0.f, ss = 0.f;
#pragma unroll
    for (int i = 0; i < 4; i++) { v[i] = xr[t + 256*i]; s += v[i]; ss += v[i]*v[i]; }
    block_reduce2(s, ss);
    float mean = s * (1.0f/DM);
    float var  = ss * (1.0f/DM) - mean*mean;
    float rs = rsqrtf(var + 1e-5f);
#pragma unroll
    for (int i = 0; i < 4; i++) {
        int d = t + 256*i;
        out[(size_t)tok*DM + d] = (bf16)((v[i]-mean)*rs*g[d] + b[d]);
    }
}

// ---------------- generic bf16 MFMA GEMM: C = A(MxK) * Bt(NxK)^T -------------
__global__ __launch_bounds__(256, 2)
void gemm_bf16(const bf16* __restrict__ A, int lda,
               const bf16* __restrict__ Bt, int ldb, int NB,
               int M, int N, int K,
               const float* __restrict__ bias,
               const float* __restrict__ addsrc,
               float* __restrict__ Cf, bf16* __restrict__ Cb, int ldc)
{
    __shared__ __align__(16) bf16 As[128*32];
    __shared__ __align__(16) bf16 Bs[128*32];
    const int t = threadIdx.x;
    const int m0 = blockIdx.y * 128, n0 = blockIdx.x * 128;
    const int lane = t & 63, wave = t >> 6;
    const int wm = (wave >> 1) * 64, wn = (wave & 1) * 64;
    const int lr = lane & 15, lq = lane >> 4;
    f32x4 acc[4][4];
#pragma unroll
    for (int i = 0; i < 4; i++)
#pragma unroll
        for (int j = 0; j < 4; j++)
#pragma unroll
            for (int r = 0; r < 4; r++) acc[i][j][r] = 0.f;
    const int srow = t >> 2, scol = (t & 3) * 8;

    for (int k0 = 0; k0 < K; k0 += 32) {
        bf16x8 a0 = zero8(), a1 = zero8(), b0 = zero8(), b1 = zero8();
        int ar0 = m0 + srow, ar1 = ar0 + 64;
        int br0 = n0 + srow, br1 = br0 + 64;
        if (ar0 < M)  a0 = *(const bf16x8*)&A [(size_t)ar0*lda + k0 + scol];
        if (ar1 < M)  a1 = *(const bf16x8*)&A [(size_t)ar1*lda + k0 + scol];
        if (br0 < NB) b0 = *(const bf16x8*)&Bt[(size_t)br0*ldb + k0 + scol];
        if (br1 < NB) b1 = *(const bf16x8*)&Bt[(size_t)br1*ldb + k0 + scol];
        __syncthreads();
        *(bf16x8*)&As[srow*32 + scol]      = a0;
        *(bf16x8*)&As[(srow+64)*32 + scol] = a1;
        *(bf16x8*)&Bs[srow*32 + scol]      = b0;
        *(bf16x8*)&Bs[(srow+64)*32 + scol] = b1;
        __syncthreads();
        bf16x8 af[4], bg[4];
#pragma unroll
        for (int i = 0; i < 4; i++) af[i] = *(const bf16x8*)&As[(wm + i*16 + lr)*32 + lq*8];
#pragma unroll
        for (int j = 0; j < 4; j++) bg[j] = *(const bf16x8*)&Bs[(wn + j*16 + lr)*32 + lq*8];
#pragma unroll
        for (int i = 0; i < 4; i++)
#pragma unroll
            for (int j = 0; j < 4; j++)
                acc[i][j] = __builtin_amdgcn_mfma_f32_16x16x32_bf16(af[i], bg[j], acc[i][j], 0, 0, 0);
    }
#pragma unroll
    for (int i = 0; i < 4; i++) {
#pragma unroll
        for (int j = 0; j < 4; j++) {
            int col = n0 + wn + j*16 + lr;
            if (col >= N) continue;
            float bv = bias ? bias[col] : 0.f;
#pragma unroll
            for (int r = 0; r < 4; r++) {
                int m = m0 + wm + i*16 + lq*4 + r;
                if (m >= M) continue;
                float v = acc[i][j][r] + bv;
                if (addsrc) v += addsrc[(size_t)m*ldc + col];
                if (Cf) Cf[(size_t)m*ldc + col] = v;
                if (Cb) Cb[(size_t)m*ldc + col] = (bf16)v;
            }
        }
    }
}

// ---------------- grouped MoE GEMM (expert chosen by 128-aligned row block) --
__global__ __launch_bounds__(256, 2)
void moe_gemm(const bf16* __restrict__ A, int lda,
              const bf16* __restrict__ WtBase, size_t wstride, int ldb,
              const float* __restrict__ biasBase, int biasStride,
              const int* __restrict__ off, int N, int K,
              bf16* __restrict__ Cb, float* __restrict__ Cf, int ldc, int gelu)
{
    const int m0 = blockIdx.y * 128;
    const int total = off[8];
    if (m0 >= total) return;
    int e = 0;
    while (e < 7 && m0 >= off[e+1]) e++;
    const bf16*  Bt   = WtBase  + (size_t)e * wstride;
    const float* bias = biasBase + (size_t)e * biasStride;

    __shared__ __align__(16) bf16 As[128*32];
    __shared__ __align__(16) bf16 Bs[128*32];
    const int t = threadIdx.x;
    const int n0 = blockIdx.x * 128;
    const int lane = t & 63, wave = t >> 6;
    const int wm = (wave >> 1) * 64, wn = (wave & 1) * 64;
    const int lr = lane & 15, lq = lane >> 4;
    f32x4 acc[4][4];
#pragma unroll
    for (int i = 0; i < 4; i++)
#pragma unroll
        for (int j = 0; j < 4; j++)
#pragma unroll
            for (int r = 0; r < 4; r++) acc[i][j][r] = 0.f;
    const int srow = t >> 2, scol = (t & 3) * 8;

    for (int k0 = 0; k0 < K; k0 += 32) {
        bf16x8 a0 = *(const bf16x8*)&A [(size_t)(m0+srow)    *lda + k0 + scol];
        bf16x8 a1 = *(const bf16x8*)&A [(size_t)(m0+srow+64) *lda + k0 + scol];
        bf16x8 b0 = *(const bf16x8*)&Bt[(size_t)(n0+srow)    *ldb + k0 + scol];
        bf16x8 b1 = *(const bf16x8*)&Bt[(size_t)(n0+srow+64) *ldb + k0 + scol];
        __syncthreads();
        *(bf16x8*)&As[srow*32 + scol]      = a0;
        *(bf16x8*)&As[(srow+64)*32 + scol] = a1;
        *(bf16x8*)&Bs[srow*32 + scol]      = b0;
        *(bf16x8*)&Bs[(srow+64)*32 + scol] = b1;
        __syncthreads();
        bf16x8 af[4], bg[4];
#pragma unroll
        for (int i = 0; i < 4; i++) af[i] = *(const bf16x8*)&As[(wm + i*16 + lr)*32 + lq*8];
#pragma unroll
        for (int j = 0; j < 4; j++) bg[j] = *(const bf16x8*)&Bs[(wn + j*16 + lr)*32 + lq*8];
#pragma unroll
        for (int i = 0; i < 4; i++)
#pragma unroll
            for (int j = 0; j < 4; j++)
                acc[i][j] = __builtin_amdgcn_mfma_f32_16x16x32_bf16(af[i], bg[j], acc[i][j], 0, 0, 0);
    }
#pragma unroll
    for (int i = 0; i < 4; i++) {
#pragma unroll
        for (int j = 0; j < 4; j++) {
            int col = n0 + wn + j*16 + lr;
            float bv = bias[col];
#pragma unroll
            for (int r = 0; r < 4; r++) {
                int m = m0 + wm + i*16 + lq*4 + r;
                float v = acc[i][j][r] + bv;
                if (gelu) v = 0.5f * v * (1.0f + erff(v * 0.70710678118f));
                if (Cb) Cb[(size_t)m*ldc + col] = (bf16)v;
                if (Cf) Cf[(size_t)m*ldc + col] = v;
            }
        }
    }
}

// ---------------- RoPE: q (f32) -> qb (bf16, *0.125) -------------------------
__global__ __launch_bounds__(256)
void rope_q_kernel(const float* __restrict__ q, bf16* __restrict__ qb)
{
    int tok = blockIdx.x, t = threadIdx.x;
    int pos = tok & (SEQ - 1);
    const float LOG1e4_32 = 0.2878231366f;  // ln(10000)/32
#pragma unroll
    for (int i = 0; i < 2; i++) {
        int p = t + 256*i;          // 0..511 = 16 heads * 32 freqs
        int hh = p >> 5, fi = p & 31;
        float inv = __expf(-(float)fi * LOG1e4_32);
        float ang = (float)pos * inv;
        float c = cosf(ang), sn = sinf(ang);
        const float* base = q + (size_t)tok*DM + hh*HDIM + 2*fi;
        float x1 = base[0], x2 = base[1];
        bf16* ob = qb + (size_t)tok*DM + hh*HDIM + 2*fi;
        ob[0] = (bf16)((x1*c - x2*sn) * 0.125f);
        ob[1] = (bf16)((x1*sn + x2*c) * 0.125f);
    }
}

// ---------------- RoPE k: kv f32 -> kb bf16 [b][kvh][s][64] ------------------
__global__ __launch_bounds__(256)
void rope_k_kernel(const float* __restrict__ kv, bf16* __restrict__ kb)
{
    int tok = blockIdx.x, t = threadIdx.x;
    int pos = tok & (SEQ - 1);
    int b = tok >> 11;          // tok / SEQ
    int s = tok & (SEQ - 1);
    int kvh = t >> 6, d = t & 63;
    int fi = d >> 1;
    const float LOG1e4_32 = 0.2878231366f;
    float inv = __expf(-(float)fi * LOG1e4_32);
    float ang = (float)pos * inv;
    float c = cosf(ang), sn = sinf(ang);
    const float* kbp = kv + (size_t)tok*512 + (size_t)(kvh*HDIM + 2*fi)*2;
    float x1 = kbp[0], x2 = kbp[2];
    float val = (d & 1) ? (x1*sn + x2*c) : (x1*c - x2*sn);
    kb[(size_t)((b*NKVH + kvh)*SEQ + s)*HDIM + d] = (bf16)val;
}

// ---------------- v transpose: kv f32 -> vt bf16 [b][kvh][64][S] -------------
__global__ __launch_bounds__(256)
void vtrans_kernel(const float* __restrict__ kv, bf16* __restrict__ vt)
{
    __shared__ float tile[32][33];
    int s0 = blockIdx.x * 32, d0 = blockIdx.y * 32;
    int bkvh = blockIdx.z;                  // 0..7
    int b = bkvh >> 2, kvh = bkvh & 3;
    int tx = threadIdx.x & 31, ty = threadIdx.x >> 5;
#pragma unroll
    for (int i = 0; i < 4; i++) {
        int s = s0 + ty + i*8;
        tile[ty + i*8][tx] = kv[(size_t)(b*SEQ + s)*512 + (size_t)(kvh*HDIM + d0 + tx)*2 + 1];
    }
    __syncthreads();
#pragma unroll
    for (int i = 0; i < 4; i++) {
        int d = d0 + ty + i*8;
        vt[(size_t)((b*NKVH + kvh)*HDIM + d)*SEQ + s0 + tx] = (bf16)tile[tx][ty + i*8];
    }
}

// ---------------- MFMA causal flash attention, GQA 16q/4kv -------------------
// Block: 64 q-rows for one (b,h). 4 waves x 16 rows. K-tiles of 64.
// LDS rows padded to 72 bf16 (144 B = 16B-aligned, 2-way banks = free).
__global__ __launch_bounds__(256)
void attn_mfma_kernel(const bf16* __restrict__ qb, const bf16* __restrict__ kb,
                      const bf16* __restrict__ vt, bf16* __restrict__ o)
{
    __shared__ __align__(16) bf16 Ks[64*72];
    __shared__ __align__(16) bf16 Vs[64*72];
    __shared__ __align__(16) bf16 Pl[4*16*72];
    const int qt = gridDim.x - 1 - blockIdx.x;   // heavy tiles first
    const int bh = blockIdx.y;
    const int b = bh >> 4, h = bh & 15, kvh = h >> 2;
    const int t = threadIdx.x, lane = t & 63, wave = t >> 6;
    const int L = lane & 15, quad = lane >> 4;
    const bf16* kbase = kb + (size_t)(b*NKVH + kvh) * SEQ * HDIM;
    const bf16* vbase = vt + (size_t)(b*NKVH + kvh) * HDIM * SEQ;
    bf16* Pw = Pl + wave * 16 * 72;

    const int qrow = qt*64 + wave*16 + L;        // this lane's Q-fragment row
    const bf16x8 qf0 = *(const bf16x8*)&qb[(size_t)(b*SEQ + qrow)*DM + h*HDIM + quad*8];
    const bf16x8 qf1 = *(const bf16x8*)&qb[(size_t)(b*SEQ + qrow)*DM + h*HDIM + 32 + quad*8];

    f32x4 Oa[4];
#pragma unroll
    for (int j = 0; j < 4; j++)
#pragma unroll
        for (int r = 0; r < 4; r++) Oa[j][r] = 0.f;
    float mrow[4] = {-1e30f, -1e30f, -1e30f, -1e30f};
    float lrow[4] = {0.f, 0.f, 0.f, 0.f};

    for (int kt = 0; kt <= qt; kt++) {
        __syncthreads();
#pragma unroll
        for (int i = 0; i < 2; i++) {
            int f = t + i*256;            // 0..511
            int row = f >> 3, ch = (f & 7) * 8;
            *(bf16x8*)&Ks[row*72 + ch] = *(const bf16x8*)&kbase[(size_t)(kt*64 + row)*HDIM + ch];
            *(bf16x8*)&Vs[row*72 + ch] = *(const bf16x8*)&vbase[(size_t)row*SEQ + kt*64 + ch];
        }
        __syncthreads();
        // S = Q K^T  (C layout: col key = nb*16+L, row q = quad*4+r)
        f32x4 S[4];
#pragma unroll
        for (int nb = 0; nb < 4; nb++) {
#pragma unroll
            for (int r = 0; r < 4; r++) S[nb][r] = 0.f;
            bf16x8 kf0 = *(const bf16x8*)&Ks[(nb*16 + L)*72 + quad*8];
            bf16x8 kf1 = *(const bf16x8*)&Ks[(nb*16 + L)*72 + 32 + quad*8];
            S[nb] = __builtin_amdgcn_mfma_f32_16x16x32_bf16(qf0, kf0, S[nb], 0, 0, 0);
            S[nb] = __builtin_amdgcn_mfma_f32_16x16x32_bf16(qf1, kf1, S[nb], 0, 0, 0);
        }
        if (kt == qt) {      // diagonal tile: mask kloc > qloc
#pragma unroll
            for (int nb = 0; nb < 4; nb++) {
                int kloc = nb*16 + L;
#pragma unroll
                for (int r = 0; r < 4; r++) {
                    int qloc = wave*16 + quad*4 + r;
                    if (kloc > qloc) S[nb][r] = -1e30f;
                }
            }
        }
        // online softmax (state per r = q-row quad*4+r)
        float alpha[4];
#pragma unroll
        for (int r = 0; r < 4; r++) {
            float mt = fmaxf(fmaxf(S[0][r], S[1][r]), fmaxf(S[2][r], S[3][r]));
#pragma unroll
            for (int w = 1; w <= 8; w <<= 1) mt = fmaxf(mt, __shfl_xor(mt, w, 64));
            float mn = fmaxf(mrow[r], mt);
            alpha[r] = __expf(mrow[r] - mn);
            mrow[r] = mn;
        }
        float rs[4] = {0.f, 0.f, 0.f, 0.f};
#pragma unroll
        for (int nb = 0; nb < 4; nb++) {
#pragma unroll
            for (int r = 0; r < 4; r++) {
                float p = __expf(S[nb][r] - mrow[r]);
                Pw[(quad*4 + r)*72 + nb*16 + L] = (bf16)p;
                rs[r] += p;
            }
        }
#pragma unroll
        for (int r = 0; r < 4; r++) {
            float v = rs[r];
#pragma unroll
            for (int w = 1; w <= 8; w <<= 1) v += __shfl_xor(v, w, 64);
            lrow[r] = lrow[r]*alpha[r] + v;
#pragma unroll
            for (int j = 0; j < 4; j++) Oa[j][r] *= alpha[r];
        }
        // PV: A = P (LDS round-trip, per-wave region), B = Vt rows
        bf16x8 pf0 = *(const bf16x8*)&Pw[L*72 + quad*8];
        bf16x8 pf1 = *(const bf16x8*)&Pw[L*72 + 32 + quad*8];
#pragma unroll
        for (int j = 0; j < 4; j++) {
            bf16x8 vf0 = *(const bf16x8*)&Vs[(j*16 + L)*72 + quad*8];
            bf16x8 vf1 = *(const bf16x8*)&Vs[(j*16 + L)*72 + 32 + quad*8];
            Oa[j] = __builtin_amdgcn_mfma_f32_16x16x32_bf16(pf0, vf0, Oa[j], 0, 0, 0);
            Oa[j] = __builtin_amdgcn_mfma_f32_16x16x32_bf16(pf1, vf1, Oa[j], 0, 0, 0);
        }
    }
    // epilogue: row = quad*4+r, col d = j*16+L
#pragma unroll
    for (int r = 0; r < 4; r++) {
        float inv = 1.0f / lrow[r];
        int row = qt*64 + wave*16 + quad*4 + r;
        bf16* op = o + (size_t)(b*SEQ + row)*DM + h*HDIM + L;
#pragma unroll
        for (int j = 0; j < 4; j++) op[j*16] = (bf16)(Oa[j][r] * inv);
    }
}

// ---------------- fused f32 LN + router + top-2 (one wave per token) ---------
__global__ __launch_bounds__(256)
void router_kernel(const float* __restrict__ x2, const float* __restrict__ lg,
                   const float* __restrict__ lb, const float* __restrict__ rw,
                   float* __restrict__ logits, int* __restrict__ topi,
                   float* __restrict__ topg, int* __restrict__ cnt)
{
    int tok = blockIdx.x * 4 + (threadIdx.x >> 6);
    int lane = threadIdx.x & 63;
    const float* xr = x2 + (size_t)tok * DM;
    float v[16], s = 0.f, ss = 0.f;
#pragma unroll
    for (int i = 0; i < 16; i++) {
        v[i] = xr[lane + 64*i];
        s += v[i]; ss += v[i]*v[i];
    }
#pragma unroll
    for (int w = 32; w; w >>= 1) { s += __shfl_xor(s, w, 64); ss += __shfl_xor(ss, w, 64); }
    float mean = s * (1.0f/DM);
    float var  = ss * (1.0f/DM) - mean*mean;
    float rs = rsqrtf(var + 1e-5f);
    float acc[8];
#pragma unroll
    for (int e = 0; e < 8; e++) acc[e] = 0.f;
#pragma unroll
    for (int i = 0; i < 16; i++) {
        int d = lane + 64*i;
        float hn = (v[i] - mean) * rs * lg[d] + lb[d];
        const float* w = rw + (size_t)d * 8;
#pragma unroll
        for (int e = 0; e < 8; e++) acc[e] += hn * w[e];
    }
#pragma unroll
    for (int e = 0; e < 8; e++) {
        float t = acc[e];
#pragma unroll
        for (int w = 32; w; w >>= 1) t += __shfl_xor(t, w, 64);
        acc[e] = t;
    }
    if (lane == 0) {
#pragma unroll
        for (int e = 0; e < 8; e++) logits[(size_t)tok*8 + e] = acc[e];
        int i1 = 0;
        for (int e = 1; e < 8; e++) if (acc[e] > acc[i1]) i1 = e;
        int i2 = (i1 == 0) ? 1 : 0;
        for (int e = 0; e < 8; e++) if (e != i1 && acc[e] > acc[i2]) i2 = e;
        float ex = __expf(acc[i2] - acc[i1]);
        float g1 = 1.f / (1.f + ex);
        topi[tok*2] = i1; topi[tok*2 + 1] = i2;
        topg[tok*2] = g1; topg[tok*2 + 1] = 1.f - g1;
        atomicAdd(&cnt[i1], 1);
        atomicAdd(&cnt[i2], 1);
    }
}

__global__ void scan_kernel(int* ctrl)   // ctrl: [0..7]=cnt [8..15]=fill [16..24]=off
{
    if (threadIdx.x == 0) {
        int run = 0;
#pragma unroll
        for (int e = 0; e < 8; e++) {
            ctrl[16 + e] = run;
            run += (ctrl[e] + 127) & ~127;
        }
        ctrl[24] = run;
    }
}

__global__ __launch_bounds__(256)
void fill_kernel(const int* __restrict__ topi, const float* __restrict__ topg,
                 int* ctrl, int* __restrict__ pair_token, int* __restrict__ token_slot)
{
    int tok = blockIdx.x * 256 + threadIdx.x;
    int* fill = ctrl + 8;
    const int* off = ctrl + 16;
#pragma unroll
    for (int kth = 0; kth < 2; kth++) {
        int e = topi[tok*2 + kth];
        int slot = off[e] + atomicAdd(&fill[e], 1);
        pair_token[slot] = tok;
        token_slot[tok*2 + kth] = slot;
    }
}

__global__ __launch_bounds__(256)
void gather_kernel(const bf16* __restrict__ h2, const int* __restrict__ pair_token,
                   bf16* __restrict__ Am)
{
    int slot = blockIdx.x, t = threadIdx.x;
    int tok = pair_token[slot];
    uint2* dst = (uint2*)(Am + (size_t)slot * DM);
    if (tok >= 0) {
        const uint2* src = (const uint2*)(h2 + (size_t)tok * DM);
        dst[t] = src[t];
    } else {
        uint2 z; z.x = 0u; z.y = 0u;
        dst[t] = z;
    }
}

// ---------------- final: gate-combine pairs, moe layernorm, residual ---------
__global__ __launch_bounds__(256)
void final_kernel(const float* __restrict__ x2, const float* __restrict__ y,
                  const int* __restrict__ token_slot, const float* __restrict__ topg,
                  const float* __restrict__ g, const float* __restrict__ b,
                  float* __restrict__ out)
{
    int tok = blockIdx.x, t = threadIdx.x;
    int s0 = token_slot[tok*2], s1 = token_slot[tok*2 + 1];
    float g0 = topg[tok*2], g1 = topg[tok*2 + 1];
    float v[4], s = 0.f, ss = 0.f;
#pragma unroll
    for (int i = 0; i < 4; i++) {
        int d = t + 256*i;
        float mv = g0 * y[(size_t)s0*DM + d] + g1 * y[(size_t)s1*DM + d];
        v[i] = mv; s += mv; ss += mv*mv;
    }
    block_reduce2(s, ss);
    float mean = s * (1.0f/DM);
    float var  = ss * (1.0f/DM) - mean*mean;
    float rs = rsqrtf(var + 1e-5f);
#pragma unroll
    for (int i = 0; i < 4; i++) {
        int d = t + 256*i;
        out[(size_t)tok*DM + d] = x2[(size_t)tok*DM + d] + (v[i]-mean)*rs*g[d] + b[d];
    }
}

// =============================================================================
extern "C" void kernel_launch(void* const* d_in, const int* in_sizes, int n_in,
                              void* d_out, int out_size, void* d_ws, size_t ws_size,
                              hipStream_t stream)
{
    const float* x        = (const float*)d_in[0];
    const float* ln1_g    = (const float*)d_in[1];
    const float* ln1_b    = (const float*)d_in[2];
    const float* q_a_w    = (const float*)d_in[3];
    const float* q_b_w    = (const float*)d_in[4];
    const float* kv_a_w   = (const float*)d_in[5];
    const float* kv_b_w   = (const float*)d_in[6];
    const float* out_w    = (const float*)d_in[7];
    const float* out_b    = (const float*)d_in[8];
    const float* ln2_g    = (const float*)d_in[9];
    const float* ln2_b    = (const float*)d_in[10];
    const float* router_w = (const float*)d_in[11];
    const float* fc_w     = (const float*)d_in[12];
    const float* fc_b     = (const float*)d_in[13];
    const float* proj_w   = (const float*)d_in[14];
    const float* proj_b   = (const float*)d_in[15];
    const float* moe_ln_g = (const float*)d_in[16];
    const float* moe_ln_b = (const float*)d_in[17];

    char* ws = (char*)d_ws;
    size_t cur = 0;
    auto alloc = [&](size_t bytes) -> void* {
        void* p = ws + cur;
        cur += (bytes + 255) & ~(size_t)255;
        return p;
    };
    bf16*  h1    = (bf16*) alloc((size_t)NTOK*DM*2);
    bf16*  latwT = (bf16*) alloc((size_t)96*1024*2);   // rows 0-63 qa^T, 64-95 kva^T
    bf16*  qbT   = (bf16*) alloc((size_t)1024*64*2);
    bf16*  kvbT  = (bf16*) alloc((size_t)512*32*2);
    bf16*  outwT = (bf16*) alloc((size_t)1024*1024*2);
    bf16*  fcT   = (bf16*) alloc((size_t)NEXP*FFD*DM*2);
    bf16*  projT = (bf16*) alloc((size_t)NEXP*DM*FFD*2);
    bf16*  latb  = (bf16*) alloc((size_t)NTOK*96*2);
    float* qf    = (float*)alloc((size_t)NTOK*DM*4);
    float* kvf   = (float*)alloc((size_t)NTOK*512*4);
    bf16*  qbb   = (bf16*) alloc((size_t)NTOK*DM*2);
    bf16*  kbb   = (bf16*) alloc((size_t)NTOK*NKVH*HDIM*2);
    bf16*  vtb   = (bf16*) alloc((size_t)NTOK*NKVH*HDIM*2);
    bf16*  ob    = (bf16*) alloc((size_t)NTOK*DM*2);
    float* x2f   = (float*)alloc((size_t)NTOK*DM*4);
    bf16*  h2    = (bf16*) alloc((size_t)NTOK*DM*2);
    int*   topi  = (int*)  alloc((size_t)NTOK*2*4);
    float* topg  = (float*)alloc((size_t)NTOK*2*4);
    int*   ctrl  = (int*)  alloc(256);
    int*   pair_token = (int*)alloc((size_t)PMAX*4);
    int*   token_slot = (int*)alloc((size_t)NTOK*2*4);
    bf16*  Am    = (bf16*) alloc((size_t)PMAX*DM*2);
    bf16*  hid   = (bf16*) alloc((size_t)PMAX*FFD*2);
    float* yb    = (float*)alloc((size_t)PMAX*DM*4);
    (void)ws_size; (void)in_sizes; (void)n_in; (void)out_size;

    float* out_x      = (float*)d_out;
    float* out_logits = (float*)d_out + (size_t)NTOK*DM;

    dim3 blk(256);
    // weight transpose+cast (f32 KxN -> bf16 NxK)
    transpose_cast<<<dim3(2,32,1),  blk, 0, stream>>>(q_a_w,  latwT,            1024,   64, 1024, 0, 0);
    transpose_cast<<<dim3(1,32,1),  blk, 0, stream>>>(kv_a_w, latwT + 64*1024,  1024,   32, 1024, 0, 0);
    transpose_cast<<<dim3(32,2,1),  blk, 0, stream>>>(q_b_w,  qbT,                64, 1024,   64, 0, 0);
    transpose_cast<<<dim3(16,1,1),  blk, 0, stream>>>(kv_b_w, kvbT,               32,  512,   32, 0, 0);
    transpose_cast<<<dim3(32,32,1), blk, 0, stream>>>(out_w,  outwT,            1024, 1024, 1024, 0, 0);
    transpose_cast<<<dim3(128,32,8),blk, 0, stream>>>(fc_w,   fcT,              1024, 4096, 1024,
                                                      (size_t)1024*4096, (size_t)4096*1024);
    transpose_cast<<<dim3(32,128,8),blk, 0, stream>>>(proj_w, projT,            4096, 1024, 4096,
                                                      (size_t)4096*1024, (size_t)1024*4096);
    // ln1 -> h1
    ln_bf16_kernel<<<NTOK, blk, 0, stream>>>(x, ln1_g, ln1_b, h1);
    // latents: h1 @ [qa|kva] -> latb (4096x96 bf16)
    gemm_bf16<<<dim3(1,32), blk, 0, stream>>>(h1, 1024, latwT, 1024, 96, NTOK, 96, 1024,
                                              nullptr, nullptr, nullptr, latb, 96);
    // q = lat_q @ q_b  (K=64)
    gemm_bf16<<<dim3(8,32), blk, 0, stream>>>(latb, 96, qbT, 64, 1024, NTOK, 1024, 64,
                                              nullptr, nullptr, qf, nullptr, 1024);
    // kv = lat_kv @ kv_b (K=32)
    gemm_bf16<<<dim3(4,32), blk, 0, stream>>>(latb + 64, 96, kvbT, 32, 512, NTOK, 512, 32,
                                              nullptr, nullptr, kvf, nullptr, 512);
    rope_q_kernel<<<NTOK, blk, 0, stream>>>(qf, qbb);
    rope_k_kernel<<<NTOK, blk, 0, stream>>>(kvf, kbb);
    vtrans_kernel<<<dim3(64,2,8), blk, 0, stream>>>(kvf, vtb);
    attn_mfma_kernel<<<dim3(32,32), blk, 0, stream>>>(qbb, kbb, vtb, ob);
    // out proj + residual -> x2
    gemm_bf16<<<dim3(8,32), blk, 0, stream>>>(ob, 1024, outwT, 1024, 1024, NTOK, 1024, 1024,
                                              out_b, x, x2f, nullptr, 1024);
    // ln2 -> h2 (bf16 copy for expert GEMM input)
    ln_bf16_kernel<<<NTOK, blk, 0, stream>>>(x2f, ln2_g, ln2_b, h2);
    // routing (f32 LN fused inside — bf16 h2 noise must not flip top-2)
    hipMemsetAsync(ctrl, 0, 64, stream);
    router_kernel<<<NTOK/4, blk, 0, stream>>>(x2f, ln2_g, ln2_b, router_w,
                                              out_logits, topi, topg, ctrl);
    scan_kernel<<<1, 64, 0, stream>>>(ctrl);
    hipMemsetAsync(pair_token, 0xFF, (size_t)PMAX*4, stream);
    fill_kernel<<<NTOK/256, blk, 0, stream>>>(topi, topg, ctrl, pair_token, token_slot);
    gather_kernel<<<PMAX, blk, 0, stream>>>(h2, pair_token, Am);
    // MoE fc (gelu fused) and proj
    moe_gemm<<<dim3(FFD/128, PMAX/128), blk, 0, stream>>>(Am, 1024, fcT, (size_t)FFD*DM, 1024,
                                                          fc_b, FFD, ctrl + 16, FFD, 1024,
                                                          hid, nullptr, FFD, 1);
    moe_gemm<<<dim3(DM/128, PMAX/128), blk, 0, stream>>>(hid, FFD, projT, (size_t)DM*FFD, FFD,
                                                         proj_b, DM, ctrl + 16, DM, FFD,
                                                         nullptr, yb, DM, 0);
    // combine + moe layernorm + residual
    final_kernel<<<NTOK, blk, 0, stream>>>(x2f, yb, token_slot, topg, moe_ln_g, moe_ln_b, out_x);
}